// Round 12
// baseline (98.628 us; speedup 1.0000x reference)
//
#include <hip/hip_runtime.h>
#include <math.h>

// GaussianMixture log-density via f16 MFMA, round 12.
//
//   e[k,n] = sum_j C[k][j] * F[j][n]   (base-2 exponent, fp32 MFMA accum)
//     coeff row  (A operand):  [ a2[0..19] , b2[0..19] , L2 , 0.. ]  (K=64 pad)
//     feature col(B operand):  [ x^2_0..19 , x_0..19 , 1 , 0.. ]
//   out[n] = ln( sum_k exp2(e[k,n]) ) + LOG_NORM
//
// R11 lesson: prefetch/occupancy-shape/preamble changes all neutral -> the
// stall is the per-tile serial chain (mfma -> chained mfma -> exp2) paying
// full latency 11x per chunk at 3 waves/SIMD.
// R12: accumulate-then-exp2 in two tile groups (6+5 independent MFMA chains
// in flight), no prefetch (R10: neutral), launch_bounds(64,4) -> 4 waves/SIMD.

#define DIMS     20
#define MULT     8
#define K_COMP   168
#define KC_PAD   176            // 11 tiles of 16 components
#define NTILE    11
#define BASE_COV 0.1f
#define LOG2E    1.4426950408889634f
#define LN2      0.6931471805599453f
#define LOG_NORM -18.378770664093453f
#define CPW      4              // 16-sample chunks per wave
#define NBLK     8192           // 8192 * 64 samples = 524288 exactly

typedef _Float16 f16x8 __attribute__((ext_vector_type(8)));
typedef _Float16 f16x2 __attribute__((ext_vector_type(2)));
typedef float    f32x4 __attribute__((ext_vector_type(4)));
typedef unsigned int uint;
typedef uint u32x4 __attribute__((ext_vector_type(4)));

__device__ __forceinline__ uint pk(float lo, float hi) {
    return __builtin_bit_cast(uint, __builtin_amdgcn_cvt_pkrtz(lo, hi));
}
__device__ __forceinline__ uint pksq(uint a) {     // v_pk_mul_f16: (lo^2, hi^2)
    f16x2 v = __builtin_bit_cast(f16x2, a);
    return __builtin_bit_cast(uint, (f16x2)(v * v));
}

// ---------------- precompute: coefficient table, fragment-ordered ----------
// tbl entry e = (t*2 + h)*64 + lane  (16 B each):
//   f16x8 = C[t*16 + (lane&15)][h*32 + (lane>>4)*8 .. +7]
__global__ void gm_precompute(const float* __restrict__ alpha,
                              const float* __restrict__ mu,
                              const float* __restrict__ cov,
                              uint4* __restrict__ tbl) {
    __shared__ _Float16 C[KC_PAD][64];
    __shared__ float sh_logZ;
    const int tid = threadIdx.x;

    uint* cz = (uint*)&C[0][0];
    for (int i = tid; i < KC_PAD * 64 / 2; i += 256) cz[i] = 0u;
    __syncthreads();

    if (tid < 64) {
        float a0 = (tid       < K_COMP) ? alpha[tid]       : -1e30f;
        float a1 = (tid + 64  < K_COMP) ? alpha[tid + 64]  : -1e30f;
        float a2 = (tid + 128 < K_COMP) ? alpha[tid + 128] : -1e30f;
        float m = fmaxf(fmaxf(a0, a1), a2);
        for (int msk = 32; msk; msk >>= 1) m = fmaxf(m, __shfl_xor(m, msk, 64));
        float s = __expf(a0 - m) + __expf(a1 - m) + __expf(a2 - m);
        for (int msk = 32; msk; msk >>= 1) s += __shfl_xor(s, msk, 64);
        if (tid == 0) sh_logZ = m + __logf(s);
    }
    __syncthreads();

    if (tid < K_COMP) {
        const int   n  = tid;
        const int   i  = n / MULT;
        const float fi = (float)i;
        const float var = 1.0f;                       // EPS^2, EPS = 1.0
        float logdet = fi * __logf(var) + ((float)DIMS - fi) * __logf(BASE_COV);
        float Csum = 0.0f;
        for (int d = 0; d < DIMS; ++d) {
            float scale = (d < i) ? var : 1.0f;
            float inv   = 1.0f / (cov[n * DIMS + d] * scale);
            float mm    = mu[n * DIMS + d];
            Csum += mm * mm * inv;
            C[n][d]        = (_Float16)(-0.5f * inv * LOG2E);
            C[n][DIMS + d] = (_Float16)(mm * inv * LOG2E);
        }
        float L2 = ((alpha[n] - sh_logZ) - 0.5f * logdet - 0.5f * Csum) * LOG2E;
        C[n][2 * DIMS] = (_Float16)L2;
    } else if (tid < KC_PAD) {
        C[tid][2 * DIMS] = (_Float16)(-65504.0f);     // pad comps -> exp2 -> 0
    }
    __syncthreads();

    for (int e = tid; e < NTILE * 2 * 64; e += 256) {
        int t    = e >> 7;
        int h    = (e >> 6) & 1;
        int lane = e & 63;
        int q = lane >> 4, c = lane & 15;
        tbl[e] = *(const uint4*)&C[t * 16 + c][h * 32 + q * 8];
    }
}

// ---------------- density: 1 wave per block, 64 samples, no LDS ------------
__global__ __launch_bounds__(64, 4) void gm_density(const float* __restrict__ sample,
                                                    const f16x8* __restrict__ tbl,
                                                    float* __restrict__ out) {
    const int l = threadIdx.x;          // 0..63
    const int q = l >> 4, c = l & 15;
    const bool qa = (q & 1) != 0, qb = (q & 2) != 0;
    const uint onezero = 0x00003C00u;   // pk(1.0h, 0.0h)
    const f32x4 zero = { 0.f, 0.f, 0.f, 0.f };

    // coefficient fragments: 22 coalesced 16B loads (L1/L2-resident table)
#define LOAD_CF(T)                                                              \
    const f16x8 cf1_##T = tbl[(T) * 128 + l];                                   \
    const f16x8 cf2_##T = tbl[(T) * 128 + 64 + l];
    LOAD_CF(0) LOAD_CF(1) LOAD_CF(2) LOAD_CF(3) LOAD_CF(4) LOAD_CF(5)
    LOAD_CF(6) LOAD_CF(7) LOAD_CF(8) LOAD_CF(9) LOAD_CF(10)
#undef LOAD_CF

    const int base = blockIdx.x * (16 * CPW);

// independent MFMA chain per tile, acc named (stays SSA)
#define TILE_ACC(T, ACC)                                                        \
        f32x4 ACC = __builtin_amdgcn_mfma_f32_16x16x32_f16(cf1_##T, sf1, zero, 0, 0, 0); \
        ACC       = __builtin_amdgcn_mfma_f32_16x16x32_f16(cf2_##T, sf2, ACC,  0, 0, 0);
#define EXP_ACC(ACC)                                                            \
        p0 += __builtin_amdgcn_exp2f(ACC[0]);                                   \
        p1 += __builtin_amdgcn_exp2f(ACC[1]);                                   \
        p2 += __builtin_amdgcn_exp2f(ACC[2]);                                   \
        p3 += __builtin_amdgcn_exp2f(ACC[3]);

#define DO_CHUNK(CC)                                                            \
    {                                                                           \
        const float4* rp = (const float4*)(sample + (size_t)(base + (CC) * 16 + c) * DIMS); \
        float4 r0 = rp[0], r1 = rp[1], r2 = rp[2], r3 = rp[3], r4 = rp[4];      \
        uint q0 = pk(r0.x, r0.y), q1 = pk(r0.z, r0.w);                          \
        uint q2 = pk(r1.x, r1.y), q3 = pk(r1.z, r1.w);                          \
        uint q4 = pk(r2.x, r2.y), q5 = pk(r2.z, r2.w);                          \
        uint q6 = pk(r3.x, r3.y), q7 = pk(r3.z, r3.w);                          \
        uint q8 = pk(r4.x, r4.y), q9 = pk(r4.z, r4.w);                          \
        uint s0 = pksq(q0), s1 = pksq(q1), s2 = pksq(q2), s3 = pksq(q3);        \
        uint s4 = pksq(q4), s5 = pksq(q5), s6 = pksq(q6), s7 = pksq(q7);        \
        uint s8 = pksq(q8), s9 = pksq(q9);                                      \
        uint f1_0 = qb ? (qa ? q2 : s8) : (qa ? s4 : s0);                       \
        uint f1_1 = qb ? (qa ? q3 : s9) : (qa ? s5 : s1);                       \
        uint f1_2 = qb ? (qa ? q4 : q0) : (qa ? s6 : s2);                       \
        uint f1_3 = qb ? (qa ? q5 : q1) : (qa ? s7 : s3);                       \
        uint f2_0 = qb ? 0u : (qa ? onezero : q6);                              \
        uint f2_1 = qb ? 0u : (qa ? 0u : q7);                                   \
        uint f2_2 = qb ? 0u : (qa ? 0u : q8);                                   \
        uint f2_3 = qb ? 0u : (qa ? 0u : q9);                                   \
        u32x4 w1 = { f1_0, f1_1, f1_2, f1_3 };                                  \
        u32x4 w2 = { f2_0, f2_1, f2_2, f2_3 };                                  \
        f16x8 sf1 = __builtin_bit_cast(f16x8, w1);                              \
        f16x8 sf2 = __builtin_bit_cast(f16x8, w2);                              \
        float p0 = 0.f, p1 = 0.f, p2 = 0.f, p3 = 0.f;                           \
        /* group A: 6 independent MFMA chains in flight, then exp2 */           \
        { TILE_ACC(0, a0) TILE_ACC(1, a1) TILE_ACC(2, a2)                       \
          TILE_ACC(3, a3) TILE_ACC(4, a4) TILE_ACC(5, a5)                       \
          EXP_ACC(a0) EXP_ACC(a1) EXP_ACC(a2)                                   \
          EXP_ACC(a3) EXP_ACC(a4) EXP_ACC(a5) }                                 \
        /* group B: 5 chains, exp2 overlaps group A's tail */                   \
        { TILE_ACC(6, b0) TILE_ACC(7, b1) TILE_ACC(8, b2)                       \
          TILE_ACC(9, b3) TILE_ACC(10, b4)                                      \
          EXP_ACC(b0) EXP_ACC(b1) EXP_ACC(b2)                                   \
          EXP_ACC(b3) EXP_ACC(b4) }                                             \
        float dens = (p0 + p1) + (p2 + p3);                                     \
        dens += __shfl_xor(dens, 16, 64);                                       \
        dens += __shfl_xor(dens, 32, 64);                                       \
        if (l < 16)                                                             \
            out[base + (CC) * 16 + l] = LN2 * __builtin_amdgcn_logf(dens) + LOG_NORM; \
    }

    DO_CHUNK(0) DO_CHUNK(1) DO_CHUNK(2) DO_CHUNK(3)
#undef DO_CHUNK
#undef TILE_ACC
#undef EXP_ACC
}

extern "C" void kernel_launch(void* const* d_in, const int* in_sizes, int n_in,
                              void* d_out, int out_size, void* d_ws, size_t ws_size,
                              hipStream_t stream) {
    const float* sample = (const float*)d_in[0];
    const float* alpha  = (const float*)d_in[1];
    const float* mu     = (const float*)d_in[2];
    const float* cov    = (const float*)d_in[3];
    float* out = (float*)d_out;
    uint4* tbl = (uint4*)d_ws;      // 11*2*64*16 B = 22528 B, fragment-ordered

    gm_precompute<<<1, 256, 0, stream>>>(alpha, mu, cov, tbl);
    gm_density<<<NBLK, 64, 0, stream>>>(sample, (const f16x8*)tbl, out);
}